// Round 3
// baseline (48.081 us; speedup 1.0000x reference)
//
#include <hip/hip_runtime.h>
#include <math.h>

#define BLK 256
#define SLICE 512   // target points per block-slice

// pack: p[i] = {x, y, z, 0.5*|p|^2}; also init per-point min slots to +inf.
__global__ void hd_pack_kernel(const float* __restrict__ s1, int n1,
                               const float* __restrict__ s2, int n2,
                               float4* __restrict__ p1, float4* __restrict__ p2,
                               unsigned int* __restrict__ min1,
                               unsigned int* __restrict__ min2) {
    const int i = blockIdx.x * BLK + threadIdx.x;
    if (i < n1) {
        float x = s1[3 * i], y = s1[3 * i + 1], z = s1[3 * i + 2];
        p1[i] = make_float4(x, y, z, 0.5f * fmaf(z, z, fmaf(y, y, x * x)));
        min1[i] = 0x7F800000u;  // +inf bits
    }
    if (i < n2) {
        float x = s2[3 * i], y = s2[3 * i + 1], z = s2[3 * i + 2];
        p2[i] = make_float4(x, y, z, 0.5f * fmaf(z, z, fmaf(y, y, x * x)));
        min2[i] = 0x7F800000u;
    }
}

// v = t.w - s.t  (affine form; each VALU op reads at most 1 SGPR when t is scalar)
__device__ __forceinline__ float affv(float4 t, float4 s) {
    float d = fmaf(t.x, s.x, fmaf(t.y, s.y, t.z * s.z));
    return t.w - d;
}

// grid (ceil(maxN/BLK), ceil(maxN/SLICE), 2). Each thread: one src point in
// registers vs SLICE targets read at block-uniform addresses (-> s_load on the
// scalar pipe, broadcast via SGPR operands; no LDS). Partial per-src min d^2
// combined across slices with uint atomicMin (d^2 clamped >= 0 so the
// bit-pattern order matches float order).
__global__ void hd_min_kernel(const float4* __restrict__ p1, int n1,
                              const float4* __restrict__ p2, int n2,
                              unsigned int* __restrict__ min1,
                              unsigned int* __restrict__ min2) {
    const int dir = blockIdx.z;
    const float4* src = dir ? p2 : p1;
    const float4* tgt = dir ? p1 : p2;
    const int nSrc    = dir ? n2 : n1;
    const int nTgt    = dir ? n1 : n2;
    unsigned int* mout = dir ? min2 : min1;

    const int j0 = blockIdx.y * SLICE;
    if (j0 >= nTgt) return;                    // uniform
    if (blockIdx.x * BLK >= nSrc) return;      // uniform
    const int cnt = min(SLICE, nTgt - j0);

    const int i = blockIdx.x * BLK + threadIdx.x;
    const bool valid = (i < nSrc);
    float4 s = make_float4(0.f, 0.f, 0.f, 0.f);
    if (valid) s = src[i];                     // coalesced 16B per lane

    const float4* tp = tgt + j0;               // block-uniform base
    float m0 = INFINITY, m1 = INFINITY;

    const int c4 = cnt & ~3;
    #pragma unroll 2
    for (int c = 0; c < c4; c += 4) {
        float4 t0 = tp[c + 0];
        float4 t1 = tp[c + 1];
        float4 t2 = tp[c + 2];
        float4 t3 = tp[c + 3];
        float v0 = affv(t0, s);
        float v1 = affv(t1, s);
        float v2 = affv(t2, s);
        float v3 = affv(t3, s);
        m0 = fminf(m0, fminf(v0, v1));         // fuses to v_min3_f32
        m1 = fminf(m1, fminf(v2, v3));
    }
    for (int c = c4; c < cnt; ++c) {           // tail for generic sizes
        m0 = fminf(m0, affv(tp[c], s));
    }

    const float mv = fminf(m0, m1);
    // d^2 = 2*(|s|^2/2 + min(|t|^2/2 - s.t)); clamp tiny negative rounding
    const float d2p = fmaxf(2.0f * (mv + s.w), 0.0f);
    if (valid) atomicMin(mout + i, __float_as_uint(d2p));
}

// blockIdx.x = direction. Reduce per-point min d^2 -> {sum of sqrt, max of sqrt}.
__global__ void hd_reduce_kernel(const unsigned int* __restrict__ min1, int n1,
                                 const unsigned int* __restrict__ min2, int n2,
                                 float* __restrict__ results) {
    const int dir = blockIdx.x;
    const unsigned int* mins = (dir == 0) ? min1 : min2;
    const int n = (dir == 0) ? n1 : n2;

    float sum = 0.f, mx = 0.f;
    for (int t = threadIdx.x; t < n; t += BLK) {
        float d = sqrtf(__uint_as_float(mins[t]));
        sum += d;
        mx = fmaxf(mx, d);
    }
    for (int o = 32; o > 0; o >>= 1) {
        sum += __shfl_down(sum, o);
        mx = fmaxf(mx, __shfl_down(mx, o));
    }
    __shared__ float ssum[BLK / 64], smax[BLK / 64];
    const int wid = threadIdx.x >> 6, lid = threadIdx.x & 63;
    if (lid == 0) { ssum[wid] = sum; smax[wid] = mx; }
    __syncthreads();
    if (threadIdx.x == 0) {
        float ss = 0.f, mm = 0.f;
        for (int w = 0; w < BLK / 64; ++w) { ss += ssum[w]; mm = fmaxf(mm, smax[w]); }
        results[dir * 2 + 0] = ss;
        results[dir * 2 + 1] = mm;
    }
}

__global__ void hd_final_kernel(const float* __restrict__ results,
                                const int* __restrict__ haus,
                                const int* __restrict__ w12,
                                const int* __restrict__ w21,
                                const int* __restrict__ nout,
                                int n1, int n2, float* __restrict__ out) {
    float t12 = 0.f, t21 = 0.f;
    if (*w12 != 0) t12 = (*haus == 0) ? results[0] / (float)n1 : results[1];
    if (*w21 != 0) t21 = (*haus == 0) ? results[2] / (float)n2 : results[3];
    if (*nout == 1) {
        out[0] = t12 + t21;
    } else {
        out[0] = t12;
        out[1] = t21;
    }
}

extern "C" void kernel_launch(void* const* d_in, const int* in_sizes, int n_in,
                              void* d_out, int out_size, void* d_ws, size_t ws_size,
                              hipStream_t stream) {
    const float* s1 = (const float*)d_in[0];
    const float* s2 = (const float*)d_in[1];
    const int* haus = (const int*)d_in[2];
    const int* w12  = (const int*)d_in[3];
    const int* w21  = (const int*)d_in[4];
    const int* nout = (const int*)d_in[5];
    float* out = (float*)d_out;

    const int n1 = in_sizes[0] / 3;
    const int n2 = in_sizes[1] / 3;

    // ws layout (16B-aligned base): p1[n1] float4 | p2[n2] float4 |
    //                               min1[n1] uint | min2[n2] uint | results[4] float
    float4* p1 = (float4*)d_ws;
    float4* p2 = p1 + n1;
    unsigned int* min1 = (unsigned int*)(p2 + n2);
    unsigned int* min2 = min1 + n1;
    float* results = (float*)(min2 + n2);

    const int maxN = (n1 > n2) ? n1 : n2;
    hd_pack_kernel<<<(maxN + BLK - 1) / BLK, BLK, 0, stream>>>(s1, n1, s2, n2,
                                                               p1, p2, min1, min2);

    dim3 grid((maxN + BLK - 1) / BLK, (maxN + SLICE - 1) / SLICE, 2);
    hd_min_kernel<<<grid, BLK, 0, stream>>>(p1, n1, p2, n2, min1, min2);

    hd_reduce_kernel<<<2, BLK, 0, stream>>>(min1, n1, min2, n2, results);

    hd_final_kernel<<<1, 1, 0, stream>>>(results, haus, w12, w21, nout, n1, n2, out);
}